// Round 2
// baseline (159.956 us; speedup 1.0000x reference)
//
#include <hip/hip_runtime.h>
#include <hip/hip_bf16.h>

#define H 128
#define STEPS 64
#define F_IN 33
#define R3H 384   // 3*H

__global__ __launch_bounds__(128) void Encoder_57380763074770_kernel(
    const float* __restrict__ x,        // [64,17]
    const int*   __restrict__ ip,       // [64,8]
    const int*   __restrict__ port,     // [64,2]
    const float* __restrict__ hidden,   // [128]
    const float* __restrict__ ip_emb,   // [256,1]
    const float* __restrict__ port_emb, // [70000,4]
    const float* __restrict__ W_ih,     // [384,33] row-major
    const float* __restrict__ W_hh,     // [384,128] row-major
    const float* __restrict__ b_ih,     // [384]
    const float* __restrict__ b_hh,     // [384]
    float* __restrict__ out)            // [64*128 + 128]
{
    __shared__ float xi[F_IN];
    __shared__ float h0s[H];
    __shared__ float ghs[R3H];
    __shared__ float wih[R3H * F_IN];   // 12672 floats = 50688 B

    const int s    = blockIdx.x;        // step
    const int tid  = threadIdx.x;
    const int lane = tid & 63;
    const int wave = tid >> 6;          // 0 or 1

    // ---- stage xi = concat(x[s], ip_emb[ip[s]], port_emb[port[s]]) ----
    if (tid < 17) {
        xi[tid] = x[s * 17 + tid];
    } else if (tid < 25) {
        xi[tid] = ip_emb[ip[s * 8 + (tid - 17)]];
    } else if (tid < F_IN) {
        int c = tid - 25;               // 0..7
        xi[tid] = port_emb[port[s * 2 + (c >> 2)] * 4 + (c & 3)];
    }
    h0s[tid] = hidden[tid];

    // ---- stage W_ih into LDS, coalesced float4 (12672 % 4 == 0) ----
    {
        const float4* w4 = (const float4*)W_ih;
        float4*       l4 = (float4*)wih;
        for (int i = tid; i < (R3H * F_IN) / 4; i += 128) l4[i] = w4[i];
    }
    __syncthreads();

    // ---- gh = h0 @ W_hh^T : one row per wave-iteration, coalesced loads ----
    {
        const float h0a = h0s[lane];
        const float h0b = h0s[lane + 64];
        const int base = wave * 192;    // wave0: rows 0..191, wave1: 192..383
        #pragma unroll 4
        for (int i = 0; i < 192; ++i) {
            const int row = base + i;
            const float* wrow = W_hh + (size_t)row * H;
            float p = fmaf(h0a, wrow[lane], h0b * wrow[lane + 64]);
            #pragma unroll
            for (int m = 32; m >= 1; m >>= 1) p += __shfl_xor(p, m, 64);
            if (lane == 0) ghs[row] = p;
        }
    }
    __syncthreads();

    // ---- gi = xi @ W_ih^T + b_ih (from LDS; stride-33 is bank-conflict-free) ----
    const int j = tid;
    float gir = b_ih[j];
    float giz = b_ih[j + H];
    float gin = b_ih[j + 2 * H];
    const float* vr = wih + j * F_IN;
    const float* vz = wih + (j + H) * F_IN;
    const float* vn = wih + (j + 2 * H) * F_IN;
    #pragma unroll
    for (int k = 0; k < F_IN; ++k) {
        const float xv = xi[k];
        gir = fmaf(xv, vr[k], gir);
        giz = fmaf(xv, vz[k], giz);
        gin = fmaf(xv, vn[k], gin);
    }

    const float ghr = ghs[j]         + b_hh[j];
    const float ghz = ghs[j + H]     + b_hh[j + H];
    const float ghn = ghs[j + 2 * H] + b_hh[j + 2 * H];

    // gates (fast exp; clamp tanh arg to keep exp finite)
    const float r = 1.0f / (1.0f + __expf(-(gir + ghr)));
    const float z = 1.0f / (1.0f + __expf(-(giz + ghz)));
    float a = gin + r * ghn;
    a = fminf(fmaxf(a, -15.0f), 15.0f);
    const float e2 = __expf(2.0f * a);
    const float n = (e2 - 1.0f) / (e2 + 1.0f);
    const float o = (1.0f - z) * n + z * h0s[j];

    out[s * H + j] = o;
    if (s == STEPS - 1) out[STEPS * H + j] = o;   // new_hidden tail
}

extern "C" void kernel_launch(void* const* d_in, const int* in_sizes, int n_in,
                              void* d_out, int out_size, void* d_ws, size_t ws_size,
                              hipStream_t stream) {
    const float* x        = (const float*)d_in[0];
    const int*   ip       = (const int*)  d_in[1];
    const int*   port     = (const int*)  d_in[2];
    const float* hidden   = (const float*)d_in[3];
    const float* ip_emb   = (const float*)d_in[4];
    const float* port_emb = (const float*)d_in[5];
    const float* W_ih     = (const float*)d_in[6];
    const float* W_hh     = (const float*)d_in[7];
    const float* b_ih     = (const float*)d_in[8];
    const float* b_hh     = (const float*)d_in[9];
    float* out = (float*)d_out;

    Encoder_57380763074770_kernel<<<STEPS, H, 0, stream>>>(
        x, ip, port, hidden, ip_emb, port_emb, W_ih, W_hh, b_ih, b_hh, out);
}

// Round 3
// 76.913 us; speedup vs baseline: 2.0797x; 2.0797x over previous
//
#include <hip/hip_runtime.h>
#include <hip/hip_bf16.h>

#define H 128
#define STEPS 64
#define F_IN 33
#define R3H 384   // 3*H

// ---------- kernel 1: gh = W_hh @ h0 + b_hh, one wave per row ----------
__global__ __launch_bounds__(256) void gh_kernel(
    const float* __restrict__ hidden,   // [128]
    const float* __restrict__ W_hh,     // [384,128] row-major
    const float* __restrict__ b_hh,     // [384]
    float* __restrict__ gh)             // [384] (workspace)
{
    const int wave = threadIdx.x >> 6;            // 0..3
    const int lane = threadIdx.x & 63;
    const int row  = blockIdx.x * 4 + wave;       // 96 blocks * 4 = 384 rows
    const float* wrow = W_hh + (size_t)row * H;
    float p = wrow[lane] * hidden[lane] + wrow[lane + 64] * hidden[lane + 64];
    #pragma unroll
    for (int m = 32; m >= 1; m >>= 1) p += __shfl_xor(p, m, 64);
    if (lane == 0) gh[row] = p + b_hh[row];
}

// ---------- kernel 2: gi + gates, one block per step ----------
__global__ __launch_bounds__(128) void Encoder_57380763074770_kernel(
    const float* __restrict__ x,        // [64,17]
    const int*   __restrict__ ip,       // [64,8]
    const int*   __restrict__ port,     // [64,2]
    const float* __restrict__ hidden,   // [128]
    const float* __restrict__ ip_emb,   // [256,1]
    const float* __restrict__ port_emb, // [70000,4]
    const float* __restrict__ W_ih,     // [384,33] row-major
    const float* __restrict__ b_ih,     // [384]
    const float* __restrict__ gh,       // [384] precomputed (includes b_hh)
    float* __restrict__ out)            // [64*128 + 128]
{
    __shared__ float xi[F_IN];
    __shared__ float h0s[H];
    __shared__ float wih[R3H * F_IN];   // 12672 floats = 50688 B

    const int s   = blockIdx.x;         // step
    const int tid = threadIdx.x;

    // stage xi = concat(x[s], ip_emb[ip[s]], port_emb[port[s]])
    if (tid < 17) {
        xi[tid] = x[s * 17 + tid];
    } else if (tid < 25) {
        xi[tid] = ip_emb[ip[s * 8 + (tid - 17)]];
    } else if (tid < F_IN) {
        int c = tid - 25;               // 0..7
        xi[tid] = port_emb[port[s * 2 + (c >> 2)] * 4 + (c & 3)];
    }
    h0s[tid] = hidden[tid];

    // stage W_ih into LDS, coalesced float4 (12672 % 4 == 0); independent loads
    {
        const float4* w4 = (const float4*)W_ih;
        float4*       l4 = (float4*)wih;
        #pragma unroll
        for (int i = 0; i < (R3H * F_IN) / 4 / 128 + 1; ++i) {
            int idx = tid + i * 128;
            if (idx < (R3H * F_IN) / 4) l4[idx] = w4[idx];
        }
    }

    // pull gh rows (L2-hot, coalesced) while staging drains
    const int j = tid;
    const float ghr = gh[j];
    const float ghz = gh[j + H];
    const float ghn = gh[j + 2 * H];
    float gir = b_ih[j];
    float giz = b_ih[j + H];
    float gin = b_ih[j + 2 * H];

    __syncthreads();

    // gi = xi @ W_ih^T + b_ih (LDS, stride-33 is bank-conflict-free)
    const float* vr = wih + j * F_IN;
    const float* vz = wih + (j + H) * F_IN;
    const float* vn = wih + (j + 2 * H) * F_IN;
    #pragma unroll
    for (int k = 0; k < F_IN; ++k) {
        const float xv = xi[k];
        gir = fmaf(xv, vr[k], gir);
        giz = fmaf(xv, vz[k], giz);
        gin = fmaf(xv, vn[k], gin);
    }

    const float r = 1.0f / (1.0f + __expf(-(gir + ghr)));
    const float z = 1.0f / (1.0f + __expf(-(giz + ghz)));
    float a = gin + r * ghn;
    a = fminf(fmaxf(a, -15.0f), 15.0f);
    const float e2 = __expf(2.0f * a);
    const float n = (e2 - 1.0f) / (e2 + 1.0f);
    const float o = (1.0f - z) * n + z * h0s[j];

    out[s * H + j] = o;
    if (s == STEPS - 1) out[STEPS * H + j] = o;   // new_hidden tail
}

extern "C" void kernel_launch(void* const* d_in, const int* in_sizes, int n_in,
                              void* d_out, int out_size, void* d_ws, size_t ws_size,
                              hipStream_t stream) {
    const float* x        = (const float*)d_in[0];
    const int*   ip       = (const int*)  d_in[1];
    const int*   port     = (const int*)  d_in[2];
    const float* hidden   = (const float*)d_in[3];
    const float* ip_emb   = (const float*)d_in[4];
    const float* port_emb = (const float*)d_in[5];
    const float* W_ih     = (const float*)d_in[6];
    const float* W_hh     = (const float*)d_in[7];
    const float* b_ih     = (const float*)d_in[8];
    const float* b_hh     = (const float*)d_in[9];
    float* out = (float*)d_out;
    float* gh  = (float*)d_ws;          // 384 floats of scratch

    gh_kernel<<<96, 256, 0, stream>>>(hidden, W_hh, b_hh, gh);
    Encoder_57380763074770_kernel<<<STEPS, H, 0, stream>>>(
        x, ip, port, hidden, ip_emb, port_emb, W_ih, b_ih, gh, out);
}